// Round 7
// baseline (331.922 us; speedup 1.0000x reference)
//
#include <hip/hip_runtime.h>
#include <math.h>

// Fully-fused, occupancy-oriented:
//   k0    : w2 -> w2b bf16 [64][96] (k=s*32+ci); w3 -> w3b bf16
//   k_fused: block = ONE 16-series tile, 4 waves split the q axis by pool2
//     window ({0,1},{2,3,4},{5,6,7},{8,9} = windows 0..3). Each wave:
//     conv1+pool1 per-lane in MFMA-A layout -> conv2 MFMA -> pool2 (own
//     window) in regs -> bf16 slice into shared 16x256 LDS tile. Barrier.
//     conv3 MFMA (wave w -> cols 32w..32w+31) -> relu -> logits partials
//     -> butterfly -> partials[2048][3].
//   k_soft: 1 block, 256 thr: batch b sums its 8 block-partials, softmax.
// No HBM intermediates; only x (159 MB) is read. Grid 2048 -> 8 blocks/CU.

typedef __attribute__((ext_vector_type(8))) short bf16x8;
typedef __attribute__((ext_vector_type(4))) float f32x4;

__device__ __forceinline__ ushort f2bf(float f) {
    union { float f; uint u; } c; c.f = f;
    return (ushort)((c.u + 0x7FFFu + ((c.u >> 16) & 1u)) >> 16);   // RNE
}

#define S2 264   // LDS tile row stride in ushorts (528B = 33*16B: 16B-aligned)

__global__ void k0_prep(const float* __restrict__ w2, ushort* __restrict__ w2b,
                        const float* __restrict__ w3, ushort* __restrict__ w3b) {
    int i = blockIdx.x * 256 + threadIdx.x;
    if (i < 6144) {                     // w2[c][ci][d] -> w2b[c][d*32+ci]
        int c = i / 96, r = i - c * 96;
        int ci = r / 3, d = r - ci * 3;
        w2b[c * 96 + d * 32 + ci] = f2bf(w2[i]);
    }
    int j = i - 6144;
    if (j >= 0 && j < 32768) w3b[j] = f2bf(w3[j]);
}

__global__ __launch_bounds__(256) void k_fused(
    const float* __restrict__ x,     // [32768][1216]
    const float* __restrict__ w1,    // [32][10]
    const float* __restrict__ b1,    // [32]
    const ushort* __restrict__ w2b,  // [64][96]
    const float* __restrict__ b2,    // [64]
    const ushort* __restrict__ w3b,  // [128][256]
    const float* __restrict__ b3,    // [128]
    const float* __restrict__ wl,    // [3][16384]
    float* __restrict__ partials)    // [2048][3]
{
    __shared__ ushort sh2[16 * S2];         // one 16-series x 256-k bf16 tile
    __shared__ float red[4][3];
    const int wave = threadIdx.x >> 6, lane = threadIdx.x & 63;
    const int lm   = lane & 15, quad = lane >> 4;
    const int bn0  = blockIdx.x * 16;
    const float* xr = x + (size_t)(bn0 + lm) * 1216;

    // this wave's pool2 window == its q range (wave-uniform)
    const int qb = (wave == 0) ? 0 : (wave == 1) ? 2 : (wave == 2) ? 5 : 8;
    const int qe = (wave == 0) ? 2 : (wave == 1) ? 5 : (wave == 2) ? 8 : 10;

    // hoist this lane's conv1 weights: channels quad*8..quad*8+7
    float wv[8][10], b1v[8];
    #pragma unroll
    for (int h = 0; h < 8; ++h) {
        const float* wr = w1 + (quad * 8 + h) * 10;
        #pragma unroll
        for (int kk = 0; kk < 5; ++kk) {
            float2 t = *(const float2*)(wr + 2 * kk);
            wv[h][2*kk] = t.x; wv[h][2*kk+1] = t.y;
        }
        b1v[h] = b1[quad * 8 + h];
    }
    float bias2[4];
    #pragma unroll
    for (int nt = 0; nt < 4; ++nt) bias2[nt] = b2[nt * 16 + lm];

    // ---- conv1 -> conv2 MFMA over this wave's q's, running max = pool2
    f32x4 cur[4];
    #pragma unroll
    for (int nt = 0; nt < 4; ++nt) cur[nt] = (f32x4){-3e38f,-3e38f,-3e38f,-3e38f};

    for (int q = qb; q < qe; ++q) {         // dynamic, wave-uniform bounds
        f32x4 acc[4];
        #pragma unroll
        for (int nt = 0; nt < 4; ++nt) acc[nt] = (f32x4){0.f,0.f,0.f,0.f};

        #pragma unroll
        for (int kc = 0; kc < 3; ++kc) {
            const int p = 3 * q + kc;       // conv1-pooled position
            const int base = 40 * p - 4;    // 16B-aligned window
            float xw[48];
            {
                const float4* xp4 = (const float4*)(xr + base);
                #pragma unroll
                for (int i = 0; i < 12; ++i) {
                    float4 v;
                    if (i == 0) {
                        if (base >= 0) v = xp4[0];                  // uniform
                        else v = make_float4(0.f, 0.f, 0.f, 0.f);   // p==0 pad
                    } else v = xp4[i];
                    xw[4*i] = v.x; xw[4*i+1] = v.y; xw[4*i+2] = v.z; xw[4*i+3] = v.w;
                }
            }
            union { ushort u[8]; bf16x8 v; } af;
            #pragma unroll
            for (int h = 0; h < 8; ++h) {   // conv1 K=10 s=8 p=1 + relu + pool5
                float mx = 0.f;
                #pragma unroll
                for (int dt = 0; dt < 5; ++dt) {
                    float a = b1v[h];
                    #pragma unroll
                    for (int k = 0; k < 10; ++k)
                        a = fmaf(wv[h][k], xw[8*dt + 3 + k], a);
                    mx = fmaxf(mx, a);
                }
                af.u[h] = f2bf(mx);
            }
            #pragma unroll
            for (int nt = 0; nt < 4; ++nt) {   // w2b hot in L1
                bf16x8 bfr = *(const bf16x8*)(w2b + (nt*16+lm)*96 + kc*32 + quad*8);
                acc[nt] = __builtin_amdgcn_mfma_f32_16x16x32_bf16(af.v, bfr, acc[nt], 0, 0, 0);
            }
        }
        #pragma unroll
        for (int nt = 0; nt < 4; ++nt)
            #pragma unroll
            for (int r = 0; r < 4; ++r)
                cur[nt][r] = fmaxf(cur[nt][r], acc[nt][r]);
    }

    // pooled slice lp = wave: bias + relu, bf16 -> LDS (D: row=quad*4+r, col)
    #pragma unroll
    for (int nt = 0; nt < 4; ++nt)
        #pragma unroll
        for (int r = 0; r < 4; ++r) {
            float f = fmaxf(cur[nt][r] + bias2[nt], 0.f);
            sh2[(quad*4 + r) * S2 + (nt*16 + lm) * 4 + wave] = f2bf(f);
        }
    __syncthreads();

    // ---- conv3 GEMM (16 series x 32 cols per wave, K=256) + logits partials
    bf16x8 afr[8];
    #pragma unroll
    for (int kc = 0; kc < 8; ++kc)          // A-frag: row lm, 16B contiguous
        afr[kc] = *(const bf16x8*)(sh2 + lm * S2 + kc * 32 + quad * 8);

    const int node0 = bn0 & 127;
    const float* wlr = wl + (node0 + quad * 4) * 128 + lm;
    float a0 = 0.f, a1 = 0.f, a2 = 0.f;
    #pragma unroll
    for (int t = 0; t < 2; ++t) {
        const int nt3 = 2 * wave + t;       // wave-uniform col group
        f32x4 acc3 = (f32x4){0.f, 0.f, 0.f, 0.f};
        const ushort* bb = w3b + (size_t)(nt3 * 16 + lm) * 256 + quad * 8;
        #pragma unroll
        for (int kc = 0; kc < 8; ++kc) {
            bf16x8 bf3 = *(const bf16x8*)(bb + kc * 32);
            acc3 = __builtin_amdgcn_mfma_f32_16x16x32_bf16(afr[kc], bf3, acc3, 0, 0, 0);
        }
        const float b3v = b3[nt3 * 16 + lm];
        #pragma unroll
        for (int r = 0; r < 4; ++r) {       // feat never materialized
            float f = fmaxf(acc3[r] + b3v, 0.f);
            const float* wp = wlr + r * 128 + nt3 * 16;
            a0 = fmaf(f, wp[0],     a0);
            a1 = fmaf(f, wp[16384], a1);
            a2 = fmaf(f, wp[32768], a2);
        }
    }

    #pragma unroll
    for (int off = 32; off > 0; off >>= 1) {
        a0 += __shfl_xor(a0, off);
        a1 += __shfl_xor(a1, off);
        a2 += __shfl_xor(a2, off);
    }
    if (lane == 0) { red[wave][0] = a0; red[wave][1] = a1; red[wave][2] = a2; }
    __syncthreads();
    if (threadIdx.x < 3) {
        float s = red[0][threadIdx.x] + red[1][threadIdx.x]
                + red[2][threadIdx.x] + red[3][threadIdx.x];
        partials[blockIdx.x * 3 + threadIdx.x] = s;
    }
}

// batch b = blocks 8b..8b+7 (16 series each): sum partials + bl -> softmax
__global__ void k_soft(const float* __restrict__ partials,
                       const float* __restrict__ bl,
                       float* __restrict__ out) {
    const int b = threadIdx.x;      // 256 batches, 1 block
    float l0 = bl[0], l1 = bl[1], l2 = bl[2];
    #pragma unroll
    for (int i = 0; i < 8; ++i) {
        const float* p = partials + (size_t)(b * 8 + i) * 3;
        l0 += p[0]; l1 += p[1]; l2 += p[2];
    }
    float m  = fmaxf(l0, fmaxf(l1, l2));
    float e0 = expf(l0 - m), e1 = expf(l1 - m), e2 = expf(l2 - m);
    float s  = e0 + e1 + e2;
    out[b*3+0] = e0 / s; out[b*3+1] = e1 / s; out[b*3+2] = e2 / s;
}

extern "C" void kernel_launch(void* const* d_in, const int* in_sizes, int n_in,
                              void* d_out, int out_size, void* d_ws, size_t ws_size,
                              hipStream_t stream) {
    const float* x  = (const float*)d_in[0];
    const float* w1 = (const float*)d_in[1];
    const float* b1 = (const float*)d_in[2];
    const float* w2 = (const float*)d_in[3];
    const float* b2 = (const float*)d_in[4];
    const float* w3 = (const float*)d_in[5];
    const float* b3 = (const float*)d_in[6];
    const float* wl = (const float*)d_in[7];
    const float* bl = (const float*)d_in[8];
    float* out = (float*)d_out;

    // tiny ws: w2b 12KB | w3b 64KB | partials 24KB
    ushort* w2b      = (ushort*)d_ws;
    ushort* w3b      = (ushort*)((char*)d_ws + 16384);
    float*  partials = (float*)((char*)d_ws + 16384 + 65536);

    k0_prep<<<152, 256, 0, stream>>>(w2, w2b, w3, w3b);
    k_fused<<<2048, 256, 0, stream>>>(x, w1, b1, w2b, b2, w3b, b3, wl, partials);
    k_soft<<<1, 256, 0, stream>>>(partials, bl, out);
}